// Round 11
// baseline (3741.476 us; speedup 1.0000x reference)
//
#include <hip/hip_runtime.h>

// ---------------------------------------------------------------------------
// SanaAttention forward, MI355X (gfx950).
// Numerics (validated r4-r10): np's ReLU(q) signs must be reproduced for BOTH
// the direct attention q AND the ms-branch q (= conv of q-slot channels, so
// conv INPUTS must be bit-exact -> ALL 16.7M q-slot values bit-exact; the
// r10 two-tier flag/fix scheme failed via the ms path). k_qnp2 computes every
// q-slot value with ONE f32 accumulator, fmaf over k STRICTLY ASCENDING
// (BLAS order, bit-matches np). Speed: B(Wpack) rows are wave-uniform ->
// scalar s_load path (no LDS/VALU cost); only A via LDS. k/v channels:
// plain bf16 MFMA (gemm_kv). conv f64-acc; attn f32; attnB bf16; GEMM2 bf16;
// BN f32. r9 PASSED this numeric config at absmax 0.03125.
//
// Memory (per-batch pipeline; ws peak ~136 MB; d_out doubles as scratch):
//   ws[0,48):   qkvT_b f32 -> out2 f32 (64MB) aliases [0,64) after attention
//   ws[48,96):  msT_b f32
//   ws[96,112): xTf f32 | [112,120): xTb bf16
//   ws[120,124): Wkv bf16 | [126,130): Wpack f32 | [130,134): WoutB bf16
//   ws[134,..): BN part (512KB) + stats (8KB)
//   d_out: attnB bf16 (dead before final BN write) -> final NCHW f32
// ---------------------------------------------------------------------------

typedef short bf16x8 __attribute__((ext_vector_type(8)));
typedef float f32x4 __attribute__((ext_vector_type(4)));

__device__ __forceinline__ float bf2f(unsigned short u) {
  union { unsigned int i; float f; } w; w.i = ((unsigned int)u) << 16; return w.f;
}
__device__ __forceinline__ unsigned short f2bf(float f) {
  union { float f; unsigned int i; } w; w.f = f;
  return (unsigned short)((w.i + 0x7fffu + ((w.i >> 16) & 1u)) >> 16);
}

__device__ __forceinline__ void gload16(const void* g, void* l) {
  __builtin_amdgcn_global_load_lds(
      (const __attribute__((address_space(1))) void*)g,
      (__attribute__((address_space(3))) void*)l, 16, 0, 0);
}

static constexpr int BB = 4, CC = 1024, NN = 4096;
static constexpr int C3 = 3 * CC;     // 3072
static constexpr int C2 = 2 * CC;     // 2048
static constexpr int MROWS = BB * NN; // 16384

// --- 1) per-batch transpose: x (C,N) f32 -> xTf (N,C) f32 + xTb bf16 ---------
__global__ __launch_bounds__(256) void k_transpose_both(const float* __restrict__ x,
                                                        float* __restrict__ xTf,
                                                        unsigned short* __restrict__ xTb) {
  __shared__ float tile[32][33];
  const int c0 = blockIdx.y << 5, n0 = blockIdx.x << 5;
  const int tx = threadIdx.x & 31, ty = threadIdx.x >> 5;
#pragma unroll
  for (int i = 0; i < 32; i += 8)
    tile[ty + i][tx] = x[((size_t)(c0 + ty + i)) * NN + n0 + tx];
  __syncthreads();
#pragma unroll
  for (int i = 0; i < 32; i += 8) {
    const float v = tile[tx][ty + i];
    const size_t idx = ((size_t)(n0 + ty + i)) * CC + c0 + tx;
    xTf[idx] = v;
    xTb[idx] = f2bf(v);
  }
}

// --- 2) Wout -> bf16 ---------------------------------------------------------
__global__ void k_cvt(const float* __restrict__ src, unsigned short* __restrict__ dst, int n4) {
  int i = blockIdx.x * 256 + threadIdx.x;
  if (i < n4) {
    float4 v = ((const float4*)src)[i];
    ushort4 o;
    o.x = f2bf(v.x); o.y = f2bf(v.y); o.z = f2bf(v.z); o.w = f2bf(v.w);
    ((ushort4*)dst)[i] = o;
  }
}

// --- 2b) gather q-slot weight rows -> Wpack (1024 x 1024 f32) ----------------
__global__ __launch_bounds__(256) void k_wpack(const float* __restrict__ Wq,
                                               const float* __restrict__ Wk,
                                               const float* __restrict__ Wv,
                                               float* __restrict__ Wpack) {
  const int j = blockIdx.x;
  const int c = 24 * (j >> 3) + (j & 7);
  const float* src = (c < CC) ? (Wq + (size_t)c * CC)
                   : (c < 2 * CC) ? (Wk + (size_t)(c - CC) * CC)
                   : (Wv + (size_t)(c - 2 * CC) * CC);
  const int t = threadIdx.x;
  ((float4*)(Wpack + (size_t)j * CC))[t] = ((const float4*)src)[t];
}

// --- 2c) gather k/v-slot weight rows -> Wkv bf16 (2048 x 1024) ---------------
__global__ __launch_bounds__(256) void k_wkv(const float* __restrict__ Wq,
                                             const float* __restrict__ Wk,
                                             const float* __restrict__ Wv,
                                             unsigned short* __restrict__ Wkv) {
  const int jj = blockIdx.x;
  const int c = 24 * (jj >> 4) + 8 + (jj & 15);
  const float* src = (c < CC) ? (Wq + (size_t)c * CC)
                   : (c < 2 * CC) ? (Wk + (size_t)(c - CC) * CC)
                   : (Wv + (size_t)(c - 2 * CC) * CC);
  const int t = threadIdx.x;
  float4 v = ((const float4*)src)[t];
  ushort4 o;
  o.x = f2bf(v.x); o.y = f2bf(v.y); o.z = f2bf(v.z); o.w = f2bf(v.w);
  ((ushort4*)(Wkv + (size_t)jj * CC))[t] = o;
}

// --- 3a) gemm_kv: qkvT k/v channels = xTb @ Wkv^T (bf16 MFMA, f32 out) -------
__global__ __launch_bounds__(256) void gemm_kv(const unsigned short* __restrict__ A,
                                               const unsigned short* __restrict__ Bmat,
                                               float* __restrict__ qkvT) {
  __shared__ __align__(16) unsigned short lA[128 * 32];
  __shared__ __align__(16) unsigned short lB[128 * 32];
  const int bx = blockIdx.x, by = blockIdx.y;
  const int tid = threadIdx.x, lane = tid & 63, wid = tid >> 6;
  const int wm = wid >> 1, wn = wid & 1;
  const int K = CC;

  const int srow = wid * 32 + (lane >> 2);
  const int skoff = (lane & 3) * 8;
  const unsigned short* Ag = A + (size_t)(bx * 128 + srow) * K + skoff;
  const unsigned short* Bg = Bmat + (size_t)(by * 128 + srow) * K + skoff;
  unsigned short* lAw = &lA[(wid * 32) * 32];
  unsigned short* lBw = &lB[(wid * 32) * 32];

  f32x4 acc[4][4] = {};

  for (int kt = 0; kt < K; kt += 32) {
    gload16(Ag + kt, lAw);
    gload16(Ag + kt + (size_t)16 * K, lAw + 16 * 32);
    gload16(Bg + kt, lBw);
    gload16(Bg + kt + (size_t)16 * K, lBw + 16 * 32);
    __syncthreads();

    const int fr = lane & 15, fkk = (lane >> 4) * 8;
    bf16x8 af[4], bfr[4];
#pragma unroll
    for (int i = 0; i < 4; ++i) {
      af[i]  = *reinterpret_cast<const bf16x8*>(&lA[(wm * 64 + i * 16 + fr) * 32 + fkk]);
      bfr[i] = *reinterpret_cast<const bf16x8*>(&lB[(wn * 64 + i * 16 + fr) * 32 + fkk]);
    }
#pragma unroll
    for (int i = 0; i < 4; ++i)
#pragma unroll
      for (int j = 0; j < 4; ++j)
        acc[i][j] = __builtin_amdgcn_mfma_f32_16x16x32_bf16(af[i], bfr[j], acc[i][j], 0, 0, 0);
    __syncthreads();
  }

  const int fr = lane & 15, fg = lane >> 4;
#pragma unroll
  for (int i = 0; i < 4; ++i) {
    const int row0 = bx * 128 + wm * 64 + i * 16 + fg * 4;
#pragma unroll
    for (int j = 0; j < 4; ++j) {
      const int jj = by * 128 + wn * 64 + j * 16 + fr;     // kv-slot 0..2047
      const int c = 24 * (jj >> 4) + 8 + (jj & 15);        // stacked channel
#pragma unroll
      for (int r = 0; r < 4; ++r)
        qkvT[(size_t)(row0 + r) * C3 + c] = acc[i][j][r];
    }
  }
}

// --- 3b) k_qnp2: np/BLAS-ordered f32 GEMM for ALL q-slot channels ------------
// Bit-matches np: one f32 accumulator per output, fmaf over k ASCENDING.
// Lanes = m rows (wave-uniform j) -> B via scalar s_load path (no LDS/VALU);
// A staged in LDS ([256 m][16 k] panel, pitch 20 floats for b128 alignment).
// Block: 256 thr = 4 waves x 64 m = 256 m-rows, J=32 j-cols; grid 16x32.
__global__ __launch_bounds__(256) void k_qnp2(const float* __restrict__ xTf,
                                              const float* __restrict__ Wpack,
                                              float* __restrict__ qkvT) {
  __shared__ float lA[256 * 20];
  const int bm = blockIdx.x * 256;
  const int bj = blockIdx.y * 32;
  const int t = threadIdx.x;
  const int m_loc = t;                    // wave w lanes cover rows 64w..64w+63
  const int srow = t >> 2, sq = t & 3;    // staging: 64 rows/round, 4 qs of 4 k

  float acc[32];
#pragma unroll
  for (int j = 0; j < 32; ++j) acc[j] = 0.f;

  const float* wbase = Wpack + (size_t)bj * CC;

  for (int kp = 0; kp < CC; kp += 16) {
    // stage A panel [256][16] -> lA (pitch 20)
    float4 g[4];
#pragma unroll
    for (int r = 0; r < 4; ++r)
      g[r] = *(const float4*)(xTf + (size_t)(bm + r * 64 + srow) * CC + kp + sq * 4);
    __syncthreads();
#pragma unroll
    for (int r = 0; r < 4; ++r)
      *(float4*)&lA[(r * 64 + srow) * 20 + sq * 4] = g[r];
    __syncthreads();

    const float* lam = &lA[m_loc * 20];
    const float4 a0 = *(const float4*)(lam + 0);
    const float4 a1 = *(const float4*)(lam + 4);
    const float4 a2 = *(const float4*)(lam + 8);
    const float4 a3 = *(const float4*)(lam + 12);
#pragma unroll
    for (int j = 0; j < 32; ++j) {
      const float* wr = wbase + (size_t)j * CC + kp;   // wave-uniform -> s_load
      float s = acc[j];
      s = fmaf(a0.x, wr[0], s);   s = fmaf(a0.y, wr[1], s);
      s = fmaf(a0.z, wr[2], s);   s = fmaf(a0.w, wr[3], s);
      s = fmaf(a1.x, wr[4], s);   s = fmaf(a1.y, wr[5], s);
      s = fmaf(a1.z, wr[6], s);   s = fmaf(a1.w, wr[7], s);
      s = fmaf(a2.x, wr[8], s);   s = fmaf(a2.y, wr[9], s);
      s = fmaf(a2.z, wr[10], s);  s = fmaf(a2.w, wr[11], s);
      s = fmaf(a3.x, wr[12], s);  s = fmaf(a3.y, wr[13], s);
      s = fmaf(a3.z, wr[14], s);  s = fmaf(a3.w, wr[15], s);
      acc[j] = s;
    }
  }

  const int m = bm + m_loc;
#pragma unroll
  for (int j = 0; j < 32; ++j) {
    const int jj = bj + j;                          // q-slot 0..1023
    const int c = 24 * (jj >> 3) + (jj & 7);        // stacked channel
    qkvT[(size_t)m * C3 + c] = acc[j];
  }
}

// --- 3c) gemm_bt plain bf16 (GEMM2), f32 out ---------------------------------
__global__ __launch_bounds__(256) void gemm_bt(const unsigned short* __restrict__ A,
                                               const unsigned short* __restrict__ Bmat,
                                               float* __restrict__ Cout,
                                               int M, int N, int K) {
  __shared__ __align__(16) unsigned short lA[128 * 32];
  __shared__ __align__(16) unsigned short lB[128 * 32];
  const int bx = blockIdx.x, by = blockIdx.y;
  const int tid = threadIdx.x, lane = tid & 63, wid = tid >> 6;
  const int wm = wid >> 1, wn = wid & 1;

  const int srow = wid * 32 + (lane >> 2);
  const int skoff = (lane & 3) * 8;
  const unsigned short* Ag = A + (size_t)(bx * 128 + srow) * K + skoff;
  const unsigned short* Bg = Bmat + (size_t)(by * 128 + srow) * K + skoff;
  unsigned short* lAw = &lA[(wid * 32) * 32];
  unsigned short* lBw = &lB[(wid * 32) * 32];

  f32x4 acc[4][4] = {};

  for (int kt = 0; kt < K; kt += 32) {
    gload16(Ag + kt, lAw);
    gload16(Ag + kt + (size_t)16 * K, lAw + 16 * 32);
    gload16(Bg + kt, lBw);
    gload16(Bg + kt + (size_t)16 * K, lBw + 16 * 32);
    __syncthreads();

    const int fr = lane & 15, fkk = (lane >> 4) * 8;
    bf16x8 af[4], bfr[4];
#pragma unroll
    for (int i = 0; i < 4; ++i) {
      af[i]  = *reinterpret_cast<const bf16x8*>(&lA[(wm * 64 + i * 16 + fr) * 32 + fkk]);
      bfr[i] = *reinterpret_cast<const bf16x8*>(&lB[(wn * 64 + i * 16 + fr) * 32 + fkk]);
    }
#pragma unroll
    for (int i = 0; i < 4; ++i)
#pragma unroll
      for (int j = 0; j < 4; ++j)
        acc[i][j] = __builtin_amdgcn_mfma_f32_16x16x32_bf16(af[i], bfr[j], acc[i][j], 0, 0, 0);
    __syncthreads();
  }

  const int fr = lane & 15, fg = lane >> 4;
#pragma unroll
  for (int i = 0; i < 4; ++i) {
    const int row0 = bx * 128 + wm * 64 + i * 16 + fg * 4;
#pragma unroll
    for (int j = 0; j < 4; ++j) {
      const int col = by * 128 + wn * 64 + j * 16 + fr;
#pragma unroll
      for (int r = 0; r < 4; ++r)
        Cout[(size_t)(row0 + r) * N + col] = acc[i][j][r];
    }
  }
}

// --- 4) multiscale: depthwise 5x5 SAME + grouped 1x1, f64 accumulation -------
__global__ __launch_bounds__(256) void k_conv_ms(const float* __restrict__ qkvT,
                                                 const float* __restrict__ dw_w,
                                                 const float* __restrict__ pw_w,
                                                 float* __restrict__ msT) {
  __shared__ __align__(16) float tin[20][20][8];
  __shared__ float wdw[8][25];
  __shared__ float wpw[8][8];
  const int g = blockIdx.y;
  const int ty0 = (blockIdx.x >> 2) << 4, tx0 = (blockIdx.x & 3) << 4;
  const int tid = threadIdx.x;

  if (tid < 200) wdw[tid / 25][tid % 25] = dw_w[(size_t)(g * 8 + tid / 25) * 25 + tid % 25];
  if (tid < 64) wpw[tid >> 3][tid & 7] = pw_w[(size_t)(g * 8 + (tid >> 3)) * 8 + (tid & 7)];

  for (int p = tid; p < 400; p += 256) {
    const int iy = p / 20, ix = p % 20;
    const int gy = ty0 + iy - 2, gx = tx0 + ix - 2;
    float4 a = make_float4(0, 0, 0, 0), b4 = a;
    if (gy >= 0 && gy < 64 && gx >= 0 && gx < 64) {
      const float* s = &qkvT[((size_t)(gy * 64 + gx)) * C3 + g * 8];
      a = *(const float4*)s;
      b4 = *(const float4*)(s + 4);
    }
    *(float4*)&tin[iy][ix][0] = a;
    *(float4*)&tin[iy][ix][4] = b4;
  }
  __syncthreads();

  const int ty = tid >> 4, tx = tid & 15;
  double acc[8] = {0, 0, 0, 0, 0, 0, 0, 0};
#pragma unroll
  for (int dy = 0; dy < 5; ++dy)
#pragma unroll
    for (int dx = 0; dx < 5; ++dx) {
#pragma unroll
      for (int ci = 0; ci < 8; ++ci)
        acc[ci] += (double)wdw[ci][dy * 5 + dx] * (double)tin[ty + dy][tx + dx][ci];
    }
  float o[8];
#pragma unroll
  for (int co = 0; co < 8; ++co) {
    double s = 0.0;
#pragma unroll
    for (int ci = 0; ci < 8; ++ci) s += (double)wpw[co][ci] * acc[ci];
    o[co] = (float)s;
  }
  const int n = (ty0 + ty) * 64 + tx0 + tx;
  float* d = &msT[((size_t)n) * C3 + g * 8];
  *(float4*)d = make_float4(o[0], o[1], o[2], o[3]);
  *(float4*)(d + 4) = make_float4(o[4], o[5], o[6], o[7]);
}

// --- 5) linear attention per head (per-batch), f32, bf16 ratio out ----------
__global__ __launch_bounds__(256) void k_attn(const float* __restrict__ qkvT,
                                              const float* __restrict__ msT,
                                              unsigned short* __restrict__ attn) {
  const int h = blockIdx.x;
  const float* src = (h < 128) ? qkvT + h * 24 : msT + (h - 128) * 24;
  const int tid = threadIdx.x, lane = tid & 63, wid = tid >> 6;

  float s[72];
#pragma unroll
  for (int i = 0; i < 72; ++i) s[i] = 0.f;

  for (int n = tid; n < NN; n += 256) {
    const float* p = src + (size_t)n * C3;
    float4 k0 = *(const float4*)(p + 8), k1 = *(const float4*)(p + 12);
    float4 v0 = *(const float4*)(p + 16), v1 = *(const float4*)(p + 20);
    float kf[8] = {fmaxf(k0.x, 0.f), fmaxf(k0.y, 0.f), fmaxf(k0.z, 0.f), fmaxf(k0.w, 0.f),
                   fmaxf(k1.x, 0.f), fmaxf(k1.y, 0.f), fmaxf(k1.z, 0.f), fmaxf(k1.w, 0.f)};
    float vf[8] = {v0.x, v0.y, v0.z, v0.w, v1.x, v1.y, v1.z, v1.w};
#pragma unroll
    for (int d = 0; d < 8; ++d)
#pragma unroll
      for (int e = 0; e < 8; ++e) s[d * 8 + e] += vf[d] * kf[e];
#pragma unroll
    for (int e = 0; e < 8; ++e) s[64 + e] += kf[e];
  }

  __shared__ float red[4][72];
  __shared__ float sc[72];
#pragma unroll
  for (int i = 0; i < 72; ++i) {
    float v = s[i];
#pragma unroll
    for (int off = 32; off > 0; off >>= 1) v += __shfl_xor(v, off, 64);
    if (lane == 0) red[wid][i] = v;
  }
  __syncthreads();
  if (tid < 72) sc[tid] = red[0][tid] + red[1][tid] + red[2][tid] + red[3][tid];
  __syncthreads();

  float sl[72];
#pragma unroll
  for (int i = 0; i < 72; ++i) sl[i] = sc[i];

  for (int n = tid; n < NN; n += 256) {
    const float* p = src + (size_t)n * C3;
    float4 q0 = *(const float4*)p, q1 = *(const float4*)(p + 4);
    float qf[8] = {fmaxf(q0.x, 0.f), fmaxf(q0.y, 0.f), fmaxf(q0.z, 0.f), fmaxf(q0.w, 0.f),
                   fmaxf(q1.x, 0.f), fmaxf(q1.y, 0.f), fmaxf(q1.z, 0.f), fmaxf(q1.w, 0.f)};
    float o[9];
#pragma unroll
    for (int d = 0; d < 9; ++d) {
      float t = 0.f;
#pragma unroll
      for (int e = 0; e < 8; ++e) t += sl[d * 8 + e] * qf[e];
      o[d] = t;
    }
    const float inv = 1.f / (o[8] + 1e-15f);
    union { unsigned short u[8]; uint4 v; } res;
#pragma unroll
    for (int d = 0; d < 8; ++d) res.u[d] = f2bf(o[d] * inv);
    *(uint4*)&attn[((size_t)n) * C2 + h * 8] = res.v;
  }
}

// --- 6) BN stats -------------------------------------------------------------
__global__ __launch_bounds__(256) void k_bn_stats(const float* __restrict__ out2,
                                                  float* __restrict__ part) {
  const int ch = blockIdx.x * 256 + threadIdx.x;
  const int r0 = blockIdx.y << 8;
  float s = 0.f, s2 = 0.f;
  for (int i = 0; i < 256; ++i) {
    float v = out2[(size_t)(r0 + i) * CC + ch];
    s += v; s2 += v * v;
  }
  part[((size_t)blockIdx.y * 2 + 0) * CC + ch] = s;
  part[((size_t)blockIdx.y * 2 + 1) * CC + ch] = s2;
}

__global__ __launch_bounds__(256) void k_bn_reduce(const float* __restrict__ part,
                                                   float* __restrict__ stats) {
  const int ch = blockIdx.x * 256 + threadIdx.x;
  float s = 0.f, s2 = 0.f;
  for (int i = 0; i < 64; ++i) {
    s += part[((size_t)i * 2 + 0) * CC + ch];
    s2 += part[((size_t)i * 2 + 1) * CC + ch];
  }
  stats[ch] = s;
  stats[CC + ch] = s2;
}

// --- 7) BN apply + transpose back to NCHW f32 --------------------------------
__global__ __launch_bounds__(256) void k_bn_apply(const float* __restrict__ out2,
                                                  const float* __restrict__ stats,
                                                  const float* __restrict__ gamma,
                                                  const float* __restrict__ beta,
                                                  float* __restrict__ out) {
  __shared__ float tile[32][33];
  const int b = blockIdx.z;
  const int c0 = blockIdx.y << 5, n0 = blockIdx.x << 5;
  const int tx = threadIdx.x & 31, ty = threadIdx.x >> 5;
  const int c = c0 + tx;
  const float mean = stats[c] * (1.f / 16384.f);
  const float var = stats[CC + c] * (1.f / 16384.f) - mean * mean;
  const float scale = gamma[c] * rsqrtf(var + 1e-5f);
  const float shift = beta[c] - mean * scale;
#pragma unroll
  for (int i = 0; i < 32; i += 8)
    tile[ty + i][tx] = out2[((size_t)b * NN + n0 + ty + i) * CC + c] * scale + shift;
  __syncthreads();
#pragma unroll
  for (int i = 0; i < 32; i += 8)
    out[((size_t)b * CC + c0 + ty + i) * NN + n0 + tx] = tile[tx][ty + i];
}

// ---------------------------------------------------------------------------
extern "C" void kernel_launch(void* const* d_in, const int* in_sizes, int n_in,
                              void* d_out, int out_size, void* d_ws, size_t ws_size,
                              hipStream_t stream) {
  const float* x     = (const float*)d_in[0];
  const float* Wq    = (const float*)d_in[1];
  const float* Wk    = (const float*)d_in[2];
  const float* Wv    = (const float*)d_in[3];
  const float* dw_w  = (const float*)d_in[4];
  const float* pw_w  = (const float*)d_in[5];
  const float* Wout  = (const float*)d_in[6];
  const float* gamma = (const float*)d_in[7];
  const float* beta  = (const float*)d_in[8];
  float* out = (float*)d_out;
  (void)ws_size; (void)in_sizes; (void)n_in; (void)out_size;

  char* ws = (char*)d_ws;
  const size_t MB = 1024 * 1024;
  float*          qkvT = (float*)(ws + 0);                   // 48 MB per-batch
  float*          msT  = (float*)(ws + 48 * MB);             // 48 MB per-batch
  float*          xTf  = (float*)(ws + 96 * MB);             // 16 MB per-batch
  unsigned short* xTb  = (unsigned short*)(ws + 112 * MB);   // 8 MB per-batch
  unsigned short* Wkv  = (unsigned short*)(ws + 120 * MB);   // 4 MB
  float*          Wpack= (float*)(ws + 126 * MB);            // 4 MB
  unsigned short* WoutB= (unsigned short*)(ws + 130 * MB);   // 4 MB
  float*          part = (float*)(ws + 134 * MB);            // 512 KB
  float*          stats= (float*)(ws + 135 * MB);            // 8 KB
  float*          out2 = (float*)(ws + 0);                   // 64 MB, aliases dead qkvT/msT
  unsigned short* attnB= (unsigned short*)d_out;             // dead before BN apply

  // weights: Wkv bf16 (2048x1024 gathered k/v rows); Wpack f32; Wout bf16
  k_wkv<<<dim3(C2), 256, 0, stream>>>(Wq, Wk, Wv, Wkv);
  k_wpack<<<dim3(CC), 256, 0, stream>>>(Wq, Wk, Wv, Wpack);
  k_cvt<<<dim3(CC * C2 / 4 / 256), 256, 0, stream>>>(Wout, WoutB, CC * C2 / 4);

  // per-batch: transpose -> kv bf16 GEMM -> np-order q-slots -> conv -> attn
  for (int b = 0; b < BB; ++b) {
    k_transpose_both<<<dim3(NN / 32, CC / 32), 256, 0, stream>>>(x + (size_t)b * CC * NN, xTf, xTb);
    gemm_kv<<<dim3(NN / 128, C2 / 128), 256, 0, stream>>>(xTb, Wkv, qkvT);
    k_qnp2<<<dim3(NN / 256, CC / 32), 256, 0, stream>>>(xTf, Wpack, qkvT);
    k_conv_ms<<<dim3(16, C3 / 8), 256, 0, stream>>>(qkvT, dw_w, pw_w, msT);
    k_attn<<<dim3(256), 256, 0, stream>>>(qkvT, msT, attnB + (size_t)b * NN * C2);
  }

  // GEMM2: out2 = attnB @ Wout^T  (16384 x 1024 x 2048), f32
  gemm_bt<<<dim3(MROWS / 128, CC / 128), 256, 0, stream>>>(attnB, WoutB, out2, MROWS, CC, C2);

  // batch norm + transpose to NCHW
  k_bn_stats<<<dim3(CC / 256, 64), 256, 0, stream>>>(out2, part);
  k_bn_reduce<<<dim3(CC / 256), 256, 0, stream>>>(part, stats);
  k_bn_apply<<<dim3(NN / 32, CC / 32, BB), 256, 0, stream>>>(out2, stats, gamma, beta, out);
}

// Round 12
// 1381.506 us; speedup vs baseline: 2.7083x; 2.7083x over previous
//
#include <hip/hip_runtime.h>

// ---------------------------------------------------------------------------
// SanaAttention forward, MI355X (gfx950).
// Numerics (validated r4-r11): np's ReLU(q) signs must be reproduced for BOTH
// the direct attention q AND the ms-branch q (conv of q-slots) -> ALL 16.7M
// q-slot values bit-exact vs np: ONE f32 accumulator, fmaf over k STRICTLY
// ASCENDING (BLAS order). k_qnp3 keeps that per-element recipe (layout change
// only; r8->r9 proved layout-independence at absmax 0.03125).
// Perf model (r8: 4x4 -> 54% VALU; r9: 4x8 -> 47%): LDS:VALU ratio fixed by
// 8x8 per-thread blocking: 4 ds_read_b128 per 64 FMA -> ~78% VALU ceiling.
// k/v channels: bf16 MFMA (gemm_kv). conv f64-acc; attn f32; attnB bf16;
// GEMM2 bf16; BN f32. (r11's k_qnp2 s_load bet FAILED: compiler emits
// per-lane broadcast global loads, 740us - reverted.)
//
// Memory (per-batch pipeline; ws peak ~136 MB; d_out doubles as scratch):
//   ws[0,48):   qkvT_b f32 -> out2 f32 (64MB) aliases [0,64) after attention
//   ws[48,96):  msT_b f32
//   ws[96,112): xTf f32 | [112,120): xTb bf16
//   ws[120,124): Wkv bf16 | [126,130): Wpack f32 | [130,134): WoutB bf16
//   ws[134,..): BN part (512KB) + stats (8KB)
//   d_out: attnB bf16 (dead before final BN write) -> final NCHW f32
// ---------------------------------------------------------------------------

typedef short bf16x8 __attribute__((ext_vector_type(8)));
typedef float f32x4 __attribute__((ext_vector_type(4)));

__device__ __forceinline__ float bf2f(unsigned short u) {
  union { unsigned int i; float f; } w; w.i = ((unsigned int)u) << 16; return w.f;
}
__device__ __forceinline__ unsigned short f2bf(float f) {
  union { float f; unsigned int i; } w; w.f = f;
  return (unsigned short)((w.i + 0x7fffu + ((w.i >> 16) & 1u)) >> 16);
}

__device__ __forceinline__ void gload16(const void* g, void* l) {
  __builtin_amdgcn_global_load_lds(
      (const __attribute__((address_space(1))) void*)g,
      (__attribute__((address_space(3))) void*)l, 16, 0, 0);
}

static constexpr int BB = 4, CC = 1024, NN = 4096;
static constexpr int C3 = 3 * CC;     // 3072
static constexpr int C2 = 2 * CC;     // 2048
static constexpr int MROWS = BB * NN; // 16384

// --- 1) per-batch transpose: x (C,N) f32 -> xTf (N,C) f32 + xTb bf16 ---------
__global__ __launch_bounds__(256) void k_transpose_both(const float* __restrict__ x,
                                                        float* __restrict__ xTf,
                                                        unsigned short* __restrict__ xTb) {
  __shared__ float tile[32][33];
  const int c0 = blockIdx.y << 5, n0 = blockIdx.x << 5;
  const int tx = threadIdx.x & 31, ty = threadIdx.x >> 5;
#pragma unroll
  for (int i = 0; i < 32; i += 8)
    tile[ty + i][tx] = x[((size_t)(c0 + ty + i)) * NN + n0 + tx];
  __syncthreads();
#pragma unroll
  for (int i = 0; i < 32; i += 8) {
    const float v = tile[tx][ty + i];
    const size_t idx = ((size_t)(n0 + ty + i)) * CC + c0 + tx;
    xTf[idx] = v;
    xTb[idx] = f2bf(v);
  }
}

// --- 2) Wout -> bf16 ---------------------------------------------------------
__global__ void k_cvt(const float* __restrict__ src, unsigned short* __restrict__ dst, int n4) {
  int i = blockIdx.x * 256 + threadIdx.x;
  if (i < n4) {
    float4 v = ((const float4*)src)[i];
    ushort4 o;
    o.x = f2bf(v.x); o.y = f2bf(v.y); o.z = f2bf(v.z); o.w = f2bf(v.w);
    ((ushort4*)dst)[i] = o;
  }
}

// --- 2b) gather q-slot weight rows -> Wpack (1024 x 1024 f32) ----------------
__global__ __launch_bounds__(256) void k_wpack(const float* __restrict__ Wq,
                                               const float* __restrict__ Wk,
                                               const float* __restrict__ Wv,
                                               float* __restrict__ Wpack) {
  const int j = blockIdx.x;
  const int c = 24 * (j >> 3) + (j & 7);
  const float* src = (c < CC) ? (Wq + (size_t)c * CC)
                   : (c < 2 * CC) ? (Wk + (size_t)(c - CC) * CC)
                   : (Wv + (size_t)(c - 2 * CC) * CC);
  const int t = threadIdx.x;
  ((float4*)(Wpack + (size_t)j * CC))[t] = ((const float4*)src)[t];
}

// --- 2c) gather k/v-slot weight rows -> Wkv bf16 (2048 x 1024) ---------------
__global__ __launch_bounds__(256) void k_wkv(const float* __restrict__ Wq,
                                             const float* __restrict__ Wk,
                                             const float* __restrict__ Wv,
                                             unsigned short* __restrict__ Wkv) {
  const int jj = blockIdx.x;
  const int c = 24 * (jj >> 4) + 8 + (jj & 15);
  const float* src = (c < CC) ? (Wq + (size_t)c * CC)
                   : (c < 2 * CC) ? (Wk + (size_t)(c - CC) * CC)
                   : (Wv + (size_t)(c - 2 * CC) * CC);
  const int t = threadIdx.x;
  float4 v = ((const float4*)src)[t];
  ushort4 o;
  o.x = f2bf(v.x); o.y = f2bf(v.y); o.z = f2bf(v.z); o.w = f2bf(v.w);
  ((ushort4*)(Wkv + (size_t)jj * CC))[t] = o;
}

// --- 3a) gemm_kv: qkvT k/v channels = xTb @ Wkv^T (bf16 MFMA, f32 out) -------
__global__ __launch_bounds__(256) void gemm_kv(const unsigned short* __restrict__ A,
                                               const unsigned short* __restrict__ Bmat,
                                               float* __restrict__ qkvT) {
  __shared__ __align__(16) unsigned short lA[128 * 32];
  __shared__ __align__(16) unsigned short lB[128 * 32];
  const int bx = blockIdx.x, by = blockIdx.y;
  const int tid = threadIdx.x, lane = tid & 63, wid = tid >> 6;
  const int wm = wid >> 1, wn = wid & 1;
  const int K = CC;

  const int srow = wid * 32 + (lane >> 2);
  const int skoff = (lane & 3) * 8;
  const unsigned short* Ag = A + (size_t)(bx * 128 + srow) * K + skoff;
  const unsigned short* Bg = Bmat + (size_t)(by * 128 + srow) * K + skoff;
  unsigned short* lAw = &lA[(wid * 32) * 32];
  unsigned short* lBw = &lB[(wid * 32) * 32];

  f32x4 acc[4][4] = {};

  for (int kt = 0; kt < K; kt += 32) {
    gload16(Ag + kt, lAw);
    gload16(Ag + kt + (size_t)16 * K, lAw + 16 * 32);
    gload16(Bg + kt, lBw);
    gload16(Bg + kt + (size_t)16 * K, lBw + 16 * 32);
    __syncthreads();

    const int fr = lane & 15, fkk = (lane >> 4) * 8;
    bf16x8 af[4], bfr[4];
#pragma unroll
    for (int i = 0; i < 4; ++i) {
      af[i]  = *reinterpret_cast<const bf16x8*>(&lA[(wm * 64 + i * 16 + fr) * 32 + fkk]);
      bfr[i] = *reinterpret_cast<const bf16x8*>(&lB[(wn * 64 + i * 16 + fr) * 32 + fkk]);
    }
#pragma unroll
    for (int i = 0; i < 4; ++i)
#pragma unroll
      for (int j = 0; j < 4; ++j)
        acc[i][j] = __builtin_amdgcn_mfma_f32_16x16x32_bf16(af[i], bfr[j], acc[i][j], 0, 0, 0);
    __syncthreads();
  }

  const int fr = lane & 15, fg = lane >> 4;
#pragma unroll
  for (int i = 0; i < 4; ++i) {
    const int row0 = bx * 128 + wm * 64 + i * 16 + fg * 4;
#pragma unroll
    for (int j = 0; j < 4; ++j) {
      const int jj = by * 128 + wn * 64 + j * 16 + fr;     // kv-slot 0..2047
      const int c = 24 * (jj >> 4) + 8 + (jj & 15);        // stacked channel
#pragma unroll
      for (int r = 0; r < 4; ++r)
        qkvT[(size_t)(row0 + r) * C3 + c] = acc[i][j][r];
    }
  }
}

// --- 3b) k_qnp3: np/BLAS-ordered f32 GEMM for ALL q-slot channels ------------
// Bit-match recipe: one f32 acc per output, fmaf over k ASCENDING.
// 128x128 tile, 256 thr, 8x8 outputs/thread; A,B staged k-major [16][132];
// per kk: 4 ds_read_b128 feed 64 fmaf (LDS:VALU ~ 41:32 -> ~78% ceiling).
// T14 prefetch: next panel's global loads issued before compute.
__global__ __launch_bounds__(256) void k_qnp3(const float* __restrict__ xTf,
                                              const float* __restrict__ Wpack,
                                              float* __restrict__ qkvT) {
  constexpr int PITCH = 132;
  __shared__ float lA[16 * PITCH];
  __shared__ float lB[16 * PITCH];
  const int bm = blockIdx.x * 128, bj = blockIdx.y * 128;
  const int t = threadIdx.x;
  const int srow = t >> 1, kb = (t & 1) * 8;   // staging: row, k-half
  const int tj = t & 15, tm = t >> 4;          // compute: 8j x 8m blocks

  const float* gA = xTf + (size_t)(bm + srow) * CC + kb;
  const float* gB = Wpack + (size_t)(bj + srow) * CC + kb;

  float acc[8][8] = {};

  float4 pa0 = *(const float4*)(gA);
  float4 pa1 = *(const float4*)(gA + 4);
  float4 pb0 = *(const float4*)(gB);
  float4 pb1 = *(const float4*)(gB + 4);

  for (int kp = 0; kp < CC; kp += 16) {
    __syncthreads();   // prev compute done before overwrite (no-op 1st iter)
#pragma unroll
    for (int i = 0; i < 4; ++i) {
      lA[(kb + i) * PITCH + srow]     = pa0[i];
      lA[(kb + 4 + i) * PITCH + srow] = pa1[i];
      lB[(kb + i) * PITCH + srow]     = pb0[i];
      lB[(kb + 4 + i) * PITCH + srow] = pb1[i];
    }
    __syncthreads();
    if (kp + 16 < CC) {   // prefetch next panel (hides under compute)
      pa0 = *(const float4*)(gA + kp + 16);
      pa1 = *(const float4*)(gA + kp + 20);
      pb0 = *(const float4*)(gB + kp + 16);
      pb1 = *(const float4*)(gB + kp + 20);
    }
#pragma unroll
    for (int kk = 0; kk < 16; ++kk) {          // k strictly ascending
      const float4 a0 = *(const float4*)&lA[kk * PITCH + tm * 8];
      const float4 a1 = *(const float4*)&lA[kk * PITCH + tm * 8 + 4];
      const float4 b0 = *(const float4*)&lB[kk * PITCH + tj * 8];
      const float4 b1 = *(const float4*)&lB[kk * PITCH + tj * 8 + 4];
      const float av[8] = {a0.x, a0.y, a0.z, a0.w, a1.x, a1.y, a1.z, a1.w};
      const float bv[8] = {b0.x, b0.y, b0.z, b0.w, b1.x, b1.y, b1.z, b1.w};
#pragma unroll
      for (int i = 0; i < 8; ++i)
#pragma unroll
        for (int j = 0; j < 8; ++j)
          acc[i][j] = fmaf(av[i], bv[j], acc[i][j]);
    }
  }

  // epilogue: each thread's 8 j's = one head's q-block -> 2 float4 per row
  const int head = (bj >> 3) + tj;         // (bj + tj*8)/8
  const int cbase = 24 * head;
#pragma unroll
  for (int i = 0; i < 8; ++i) {
    const int m = bm + tm * 8 + i;
    float* d = &qkvT[(size_t)m * C3 + cbase];
    *(float4*)d = make_float4(acc[i][0], acc[i][1], acc[i][2], acc[i][3]);
    *(float4*)(d + 4) = make_float4(acc[i][4], acc[i][5], acc[i][6], acc[i][7]);
  }
}

// --- 3c) gemm_bt plain bf16 (GEMM2), f32 out ---------------------------------
__global__ __launch_bounds__(256) void gemm_bt(const unsigned short* __restrict__ A,
                                               const unsigned short* __restrict__ Bmat,
                                               float* __restrict__ Cout,
                                               int M, int N, int K) {
  __shared__ __align__(16) unsigned short lA[128 * 32];
  __shared__ __align__(16) unsigned short lB[128 * 32];
  const int bx = blockIdx.x, by = blockIdx.y;
  const int tid = threadIdx.x, lane = tid & 63, wid = tid >> 6;
  const int wm = wid >> 1, wn = wid & 1;

  const int srow = wid * 32 + (lane >> 2);
  const int skoff = (lane & 3) * 8;
  const unsigned short* Ag = A + (size_t)(bx * 128 + srow) * K + skoff;
  const unsigned short* Bg = Bmat + (size_t)(by * 128 + srow) * K + skoff;
  unsigned short* lAw = &lA[(wid * 32) * 32];
  unsigned short* lBw = &lB[(wid * 32) * 32];

  f32x4 acc[4][4] = {};

  for (int kt = 0; kt < K; kt += 32) {
    gload16(Ag + kt, lAw);
    gload16(Ag + kt + (size_t)16 * K, lAw + 16 * 32);
    gload16(Bg + kt, lBw);
    gload16(Bg + kt + (size_t)16 * K, lBw + 16 * 32);
    __syncthreads();

    const int fr = lane & 15, fkk = (lane >> 4) * 8;
    bf16x8 af[4], bfr[4];
#pragma unroll
    for (int i = 0; i < 4; ++i) {
      af[i]  = *reinterpret_cast<const bf16x8*>(&lA[(wm * 64 + i * 16 + fr) * 32 + fkk]);
      bfr[i] = *reinterpret_cast<const bf16x8*>(&lB[(wn * 64 + i * 16 + fr) * 32 + fkk]);
    }
#pragma unroll
    for (int i = 0; i < 4; ++i)
#pragma unroll
      for (int j = 0; j < 4; ++j)
        acc[i][j] = __builtin_amdgcn_mfma_f32_16x16x32_bf16(af[i], bfr[j], acc[i][j], 0, 0, 0);
    __syncthreads();
  }

  const int fr = lane & 15, fg = lane >> 4;
#pragma unroll
  for (int i = 0; i < 4; ++i) {
    const int row0 = bx * 128 + wm * 64 + i * 16 + fg * 4;
#pragma unroll
    for (int j = 0; j < 4; ++j) {
      const int col = by * 128 + wn * 64 + j * 16 + fr;
#pragma unroll
      for (int r = 0; r < 4; ++r)
        Cout[(size_t)(row0 + r) * N + col] = acc[i][j][r];
    }
  }
}

// --- 4) multiscale: depthwise 5x5 SAME + grouped 1x1, f64 accumulation -------
__global__ __launch_bounds__(256) void k_conv_ms(const float* __restrict__ qkvT,
                                                 const float* __restrict__ dw_w,
                                                 const float* __restrict__ pw_w,
                                                 float* __restrict__ msT) {
  __shared__ __align__(16) float tin[20][20][8];
  __shared__ float wdw[8][25];
  __shared__ float wpw[8][8];
  const int g = blockIdx.y;
  const int ty0 = (blockIdx.x >> 2) << 4, tx0 = (blockIdx.x & 3) << 4;
  const int tid = threadIdx.x;

  if (tid < 200) wdw[tid / 25][tid % 25] = dw_w[(size_t)(g * 8 + tid / 25) * 25 + tid % 25];
  if (tid < 64) wpw[tid >> 3][tid & 7] = pw_w[(size_t)(g * 8 + (tid >> 3)) * 8 + (tid & 7)];

  for (int p = tid; p < 400; p += 256) {
    const int iy = p / 20, ix = p % 20;
    const int gy = ty0 + iy - 2, gx = tx0 + ix - 2;
    float4 a = make_float4(0, 0, 0, 0), b4 = a;
    if (gy >= 0 && gy < 64 && gx >= 0 && gx < 64) {
      const float* s = &qkvT[((size_t)(gy * 64 + gx)) * C3 + g * 8];
      a = *(const float4*)s;
      b4 = *(const float4*)(s + 4);
    }
    *(float4*)&tin[iy][ix][0] = a;
    *(float4*)&tin[iy][ix][4] = b4;
  }
  __syncthreads();

  const int ty = tid >> 4, tx = tid & 15;
  double acc[8] = {0, 0, 0, 0, 0, 0, 0, 0};
#pragma unroll
  for (int dy = 0; dy < 5; ++dy)
#pragma unroll
    for (int dx = 0; dx < 5; ++dx) {
#pragma unroll
      for (int ci = 0; ci < 8; ++ci)
        acc[ci] += (double)wdw[ci][dy * 5 + dx] * (double)tin[ty + dy][tx + dx][ci];
    }
  float o[8];
#pragma unroll
  for (int co = 0; co < 8; ++co) {
    double s = 0.0;
#pragma unroll
    for (int ci = 0; ci < 8; ++ci) s += (double)wpw[co][ci] * acc[ci];
    o[co] = (float)s;
  }
  const int n = (ty0 + ty) * 64 + tx0 + tx;
  float* d = &msT[((size_t)n) * C3 + g * 8];
  *(float4*)d = make_float4(o[0], o[1], o[2], o[3]);
  *(float4*)(d + 4) = make_float4(o[4], o[5], o[6], o[7]);
}

// --- 5) linear attention per head (per-batch), f32, bf16 ratio out ----------
__global__ __launch_bounds__(256) void k_attn(const float* __restrict__ qkvT,
                                              const float* __restrict__ msT,
                                              unsigned short* __restrict__ attn) {
  const int h = blockIdx.x;
  const float* src = (h < 128) ? qkvT + h * 24 : msT + (h - 128) * 24;
  const int tid = threadIdx.x, lane = tid & 63, wid = tid >> 6;

  float s[72];
#pragma unroll
  for (int i = 0; i < 72; ++i) s[i] = 0.f;

  for (int n = tid; n < NN; n += 256) {
    const float* p = src + (size_t)n * C3;
    float4 k0 = *(const float4*)(p + 8), k1 = *(const float4*)(p + 12);
    float4 v0 = *(const float4*)(p + 16), v1 = *(const float4*)(p + 20);
    float kf[8] = {fmaxf(k0.x, 0.f), fmaxf(k0.y, 0.f), fmaxf(k0.z, 0.f), fmaxf(k0.w, 0.f),
                   fmaxf(k1.x, 0.f), fmaxf(k1.y, 0.f), fmaxf(k1.z, 0.f), fmaxf(k1.w, 0.f)};
    float vf[8] = {v0.x, v0.y, v0.z, v0.w, v1.x, v1.y, v1.z, v1.w};
#pragma unroll
    for (int d = 0; d < 8; ++d)
#pragma unroll
      for (int e = 0; e < 8; ++e) s[d * 8 + e] += vf[d] * kf[e];
#pragma unroll
    for (int e = 0; e < 8; ++e) s[64 + e] += kf[e];
  }

  __shared__ float red[4][72];
  __shared__ float sc[72];
#pragma unroll
  for (int i = 0; i < 72; ++i) {
    float v = s[i];
#pragma unroll
    for (int off = 32; off > 0; off >>= 1) v += __shfl_xor(v, off, 64);
    if (lane == 0) red[wid][i] = v;
  }
  __syncthreads();
  if (tid < 72) sc[tid] = red[0][tid] + red[1][tid] + red[2][tid] + red[3][tid];
  __syncthreads();

  float sl[72];
#pragma unroll
  for (int i = 0; i < 72; ++i) sl[i] = sc[i];

  for (int n = tid; n < NN; n += 256) {
    const float* p = src + (size_t)n * C3;
    float4 q0 = *(const float4*)p, q1 = *(const float4*)(p + 4);
    float qf[8] = {fmaxf(q0.x, 0.f), fmaxf(q0.y, 0.f), fmaxf(q0.z, 0.f), fmaxf(q0.w, 0.f),
                   fmaxf(q1.x, 0.f), fmaxf(q1.y, 0.f), fmaxf(q1.z, 0.f), fmaxf(q1.w, 0.f)};
    float o[9];
#pragma unroll
    for (int d = 0; d < 9; ++d) {
      float t = 0.f;
#pragma unroll
      for (int e = 0; e < 8; ++e) t += sl[d * 8 + e] * qf[e];
      o[d] = t;
    }
    const float inv = 1.f / (o[8] + 1e-15f);
    union { unsigned short u[8]; uint4 v; } res;
#pragma unroll
    for (int d = 0; d < 8; ++d) res.u[d] = f2bf(o[d] * inv);
    *(uint4*)&attn[((size_t)n) * C2 + h * 8] = res.v;
  }
}

// --- 6) BN stats -------------------------------------------------------------
__global__ __launch_bounds__(256) void k_bn_stats(const float* __restrict__ out2,
                                                  float* __restrict__ part) {
  const int ch = blockIdx.x * 256 + threadIdx.x;
  const int r0 = blockIdx.y << 8;
  float s = 0.f, s2 = 0.f;
  for (int i = 0; i < 256; ++i) {
    float v = out2[(size_t)(r0 + i) * CC + ch];
    s += v; s2 += v * v;
  }
  part[((size_t)blockIdx.y * 2 + 0) * CC + ch] = s;
  part[((size_t)blockIdx.y * 2 + 1) * CC + ch] = s2;
}

__global__ __launch_bounds__(256) void k_bn_reduce(const float* __restrict__ part,
                                                   float* __restrict__ stats) {
  const int ch = blockIdx.x * 256 + threadIdx.x;
  float s = 0.f, s2 = 0.f;
  for (int i = 0; i < 64; ++i) {
    s += part[((size_t)i * 2 + 0) * CC + ch];
    s2 += part[((size_t)i * 2 + 1) * CC + ch];
  }
  stats[ch] = s;
  stats[CC + ch] = s2;
}

// --- 7) BN apply + transpose back to NCHW f32 --------------------------------
__global__ __launch_bounds__(256) void k_bn_apply(const float* __restrict__ out2,
                                                  const float* __restrict__ stats,
                                                  const float* __restrict__ gamma,
                                                  const float* __restrict__ beta,
                                                  float* __restrict__ out) {
  __shared__ float tile[32][33];
  const int b = blockIdx.z;
  const int c0 = blockIdx.y << 5, n0 = blockIdx.x << 5;
  const int tx = threadIdx.x & 31, ty = threadIdx.x >> 5;
  const int c = c0 + tx;
  const float mean = stats[c] * (1.f / 16384.f);
  const float var = stats[CC + c] * (1.f / 16384.f) - mean * mean;
  const float scale = gamma[c] * rsqrtf(var + 1e-5f);
  const float shift = beta[c] - mean * scale;
#pragma unroll
  for (int i = 0; i < 32; i += 8)
    tile[ty + i][tx] = out2[((size_t)b * NN + n0 + ty + i) * CC + c] * scale + shift;
  __syncthreads();
#pragma unroll
  for (int i = 0; i < 32; i += 8)
    out[((size_t)b * CC + c0 + ty + i) * NN + n0 + tx] = tile[tx][ty + i];
}

// ---------------------------------------------------------------------------
extern "C" void kernel_launch(void* const* d_in, const int* in_sizes, int n_in,
                              void* d_out, int out_size, void* d_ws, size_t ws_size,
                              hipStream_t stream) {
  const float* x     = (const float*)d_in[0];
  const float* Wq    = (const float*)d_in[1];
  const float* Wk    = (const float*)d_in[2];
  const float* Wv    = (const float*)d_in[3];
  const float* dw_w  = (const float*)d_in[4];
  const float* pw_w  = (const float*)d_in[5];
  const float* Wout  = (const float*)d_in[6];
  const float* gamma = (const float*)d_in[7];
  const float* beta  = (const float*)d_in[8];
  float* out = (float*)d_out;
  (void)ws_size; (void)in_sizes; (void)n_in; (void)out_size;

  char* ws = (char*)d_ws;
  const size_t MB = 1024 * 1024;
  float*          qkvT = (float*)(ws + 0);                   // 48 MB per-batch
  float*          msT  = (float*)(ws + 48 * MB);             // 48 MB per-batch
  float*          xTf  = (float*)(ws + 96 * MB);             // 16 MB per-batch
  unsigned short* xTb  = (unsigned short*)(ws + 112 * MB);   // 8 MB per-batch
  unsigned short* Wkv  = (unsigned short*)(ws + 120 * MB);   // 4 MB
  float*          Wpack= (float*)(ws + 126 * MB);            // 4 MB
  unsigned short* WoutB= (unsigned short*)(ws + 130 * MB);   // 4 MB
  float*          part = (float*)(ws + 134 * MB);            // 512 KB
  float*          stats= (float*)(ws + 135 * MB);            // 8 KB
  float*          out2 = (float*)(ws + 0);                   // 64 MB, aliases dead qkvT/msT
  unsigned short* attnB= (unsigned short*)d_out;             // dead before BN apply

  // weights: Wkv bf16 (2048x1024 gathered k/v rows); Wpack f32; Wout bf16
  k_wkv<<<dim3(C2), 256, 0, stream>>>(Wq, Wk, Wv, Wkv);
  k_wpack<<<dim3(CC), 256, 0, stream>>>(Wq, Wk, Wv, Wpack);
  k_cvt<<<dim3(CC * C2 / 4 / 256), 256, 0, stream>>>(Wout, WoutB, CC * C2 / 4);

  // per-batch: transpose -> kv bf16 GEMM -> np-order q-slots -> conv -> attn
  for (int b = 0; b < BB; ++b) {
    k_transpose_both<<<dim3(NN / 32, CC / 32), 256, 0, stream>>>(x + (size_t)b * CC * NN, xTf, xTb);
    gemm_kv<<<dim3(NN / 128, C2 / 128), 256, 0, stream>>>(xTb, Wkv, qkvT);
    k_qnp3<<<dim3(NN / 128, CC / 128), 256, 0, stream>>>(xTf, Wpack, qkvT);
    k_conv_ms<<<dim3(16, C3 / 8), 256, 0, stream>>>(qkvT, dw_w, pw_w, msT);
    k_attn<<<dim3(256), 256, 0, stream>>>(qkvT, msT, attnB + (size_t)b * NN * C2);
  }

  // GEMM2: out2 = attnB @ Wout^T  (16384 x 1024 x 2048), f32
  gemm_bt<<<dim3(MROWS / 128, CC / 128), 256, 0, stream>>>(attnB, WoutB, out2, MROWS, CC, C2);

  // batch norm + transpose to NCHW
  k_bn_stats<<<dim3(CC / 256, 64), 256, 0, stream>>>(out2, part);
  k_bn_reduce<<<dim3(CC / 256), 256, 0, stream>>>(part, stats);
  k_bn_apply<<<dim3(NN / 32, CC / 32, BB), 256, 0, stream>>>(out2, stats, gamma, beta, out);
}